// Round 1
// baseline (49.729 us; speedup 1.0000x reference)
//
#include <hip/hip_runtime.h>
#include <stdint.h>

// ---------------------------------------------------------------------------
// Algebraic simplification of the reference:
//   * grad / softmax / top_k results are never used (dead code).
//   * kv_sel is a broadcast -> attention softmax is uniform -> attn@v_sel = v.
//   * Net computation:
//       V = x @ W_qkv[:, 1024:1536]                      (8192x512 @ 512x512)
//       Z[bi, (pi&1)*8+hi, ni, (pi>>1)*64+d] = gelu(V[bi,pi,ni,hi*64+d])
//       Y = Z @ W_out + b_out                            (8192x512 @ 512x512)
//   with b=2, p=16, n=256, h=8, dh=64, M = b*p*n = 8192, K = N = 512.
// ---------------------------------------------------------------------------

typedef __bf16 bf16x8 __attribute__((ext_vector_type(8)));
typedef float f32x4 __attribute__((ext_vector_type(4)));
typedef unsigned short u16x4 __attribute__((ext_vector_type(4)));

#define HD __device__ __forceinline__

HD uint16_t f2bf(float f) {
  union { float f; uint32_t u; } v; v.f = f;
  uint32_t u = v.u;
  u += 0x7fffu + ((u >> 16) & 1u);   // RNE
  return (uint16_t)(u >> 16);
}

HD void gll16(const void* g, void* l) {
  __builtin_amdgcn_global_load_lds(
      (__attribute__((address_space(1))) void*)g,
      (__attribute__((address_space(3))) void*)l, 16, 0, 0);
}

// ---------------------------------------------------------------------------
// W^T + fp32->bf16 convert:  out[c][k] = bf16(in[k][coloff + c]), 512x512 out.
// 64x64 tiles, 256 threads.
// ---------------------------------------------------------------------------
__global__ __launch_bounds__(256) void k_transpose_bf16(
    const float* __restrict__ in, int ldin, int coloff,
    uint16_t* __restrict__ out) {
  __shared__ uint16_t t[64][66];   // pad 66 -> conflict-free transposed read
  const int tid = threadIdx.x;
  const int tx = tid & 63;
  const int ty = tid >> 6;
  const int j0 = blockIdx.x * 64;
  const int k0 = blockIdx.y * 64;
#pragma unroll
  for (int r = 0; r < 16; ++r) {
    int k = ty * 16 + r;
    t[k][tx] = f2bf(in[(size_t)(k0 + k) * ldin + coloff + j0 + tx]);
  }
  __syncthreads();
#pragma unroll
  for (int r = 0; r < 16; ++r) {
    int j = ty * 16 + r;
    out[(size_t)(j0 + j) * 512 + k0 + tx] = t[tx][j];
  }
}

// ---------------------------------------------------------------------------
// GEMM1: V = X @ Wv, epilogue = gelu + permuted bf16 scatter into Z.
// BM=64 BN=128 BK=32, 256 thr (4 waves, each 32x64 = 2x4 frags of 16x16).
// LDS layout [kchunk][row][8] bf16 -> ds_read_b128 of an MFMA fragment is
// bank-uniform; B comes from pre-transposed bf16 W so staging is 16B granules
// via global_load_lds.
// ---------------------------------------------------------------------------
__global__ __launch_bounds__(256) void k_gemm_gelu_perm(
    const float* __restrict__ X,       // [8192][512] fp32
    const uint16_t* __restrict__ WT,   // [512][512] bf16, WT[col][k]
    uint16_t* __restrict__ Z) {        // [8192][512] bf16, permuted
  __shared__ __align__(16) uint16_t As[2][4][64][8];
  __shared__ __align__(16) uint16_t Bs[2][4][128][8];

  const int tid = threadIdx.x;
  const int lane = tid & 63;
  const int wid = tid >> 6;
  const int wm = wid >> 1;
  const int wn = wid & 1;
  const int tm = blockIdx.y * 64;
  const int tn = blockIdx.x * 128;

  f32x4 acc[2][4];
  const f32x4 zero = {0.f, 0.f, 0.f, 0.f};
#pragma unroll
  for (int i = 0; i < 2; ++i)
#pragma unroll
    for (int j = 0; j < 4; ++j) acc[i][j] = zero;

  const int ar0 = tid >> 3;   // row 0..31 (second load: +32)
  const int ac0 = tid & 7;    // float4 index within BK=32

  auto stage = [&](int kk, int buf) {
    // A: reg-staged fp32 -> bf16 (coalesced: 8 lanes cover one 128B row-chunk)
    float4 f0 = *(const float4*)(X + (size_t)(tm + ar0) * 512 + kk * 32 + ac0 * 4);
    float4 f1 = *(const float4*)(X + (size_t)(tm + ar0 + 32) * 512 + kk * 32 + ac0 * 4);
    u16x4 w0, w1;
    w0[0] = f2bf(f0.x); w0[1] = f2bf(f0.y); w0[2] = f2bf(f0.z); w0[3] = f2bf(f0.w);
    w1[0] = f2bf(f1.x); w1[1] = f2bf(f1.y); w1[2] = f2bf(f1.z); w1[3] = f2bf(f1.w);
    *(u16x4*)&As[buf][ac0 >> 1][ar0][(ac0 & 1) * 4] = w0;
    *(u16x4*)&As[buf][ac0 >> 1][ar0 + 32][(ac0 & 1) * 4] = w1;
    // B: async global->LDS, 16B granules; wave-uniform LDS base + lane*16
#pragma unroll
    for (int s = 0; s < 2; ++s) {
      int t = wid + 4 * s;
      int kc = t >> 1;
      int cb = (t & 1) * 64;
      gll16(WT + (size_t)(tn + cb + lane) * 512 + kk * 32 + kc * 8,
            &Bs[buf][kc][cb][0]);
    }
  };

  stage(0, 0);
  __syncthreads();

  const int lr = lane & 15;
  const int lk = lane >> 4;

#pragma unroll 2
  for (int kk = 0; kk < 16; ++kk) {
    const int cur = kk & 1;
    if (kk + 1 < 16) stage(kk + 1, cur ^ 1);
    bf16x8 a[2], b[4];
#pragma unroll
    for (int mi = 0; mi < 2; ++mi)
      a[mi] = *(const bf16x8*)&As[cur][lk][wm * 32 + mi * 16 + lr][0];
#pragma unroll
    for (int nj = 0; nj < 4; ++nj)
      b[nj] = *(const bf16x8*)&Bs[cur][lk][wn * 64 + nj * 16 + lr][0];
#pragma unroll
    for (int mi = 0; mi < 2; ++mi)
#pragma unroll
      for (int nj = 0; nj < 4; ++nj)
        acc[mi][nj] = __builtin_amdgcn_mfma_f32_16x16x32_bf16(
            a[mi], b[nj], acc[mi][nj], 0, 0, 0);
    __syncthreads();
  }

  // Epilogue: exact gelu + bijective permutation, bf16 scatter.
  // V element (m=(bi,pi,ni), j=(hi,di)) -> Z row (bi,(pi&1)*8+hi,ni),
  // col (pi>>1)*64 + di.
#pragma unroll
  for (int mi = 0; mi < 2; ++mi)
#pragma unroll
    for (int nj = 0; nj < 4; ++nj)
#pragma unroll
      for (int r = 0; r < 4; ++r) {
        int m = tm + wm * 32 + mi * 16 + lk * 4 + r;
        int j = tn + wn * 64 + nj * 16 + lr;
        float v = acc[mi][nj][r];
        v = 0.5f * v * (1.0f + erff(v * 0.70710678118654752440f));
        int pi = (m >> 8) & 15;
        int mp = (m & ~(15 << 8)) | ((((pi & 1) << 3) | (j >> 6)) << 8);
        int jp = ((pi >> 1) << 6) | (j & 63);
        Z[(size_t)mp * 512 + jp] = f2bf(v);
      }
}

// ---------------------------------------------------------------------------
// GEMM2: Y = Z @ Wout + bias, fp32 out. Same tiling; A also via
// global_load_lds (Z is already bf16).
// ---------------------------------------------------------------------------
__global__ __launch_bounds__(256) void k_gemm_bias(
    const uint16_t* __restrict__ Zb,   // [8192][512] bf16
    const uint16_t* __restrict__ WT,   // [512][512] bf16, WoT[col][k]
    const float* __restrict__ bias,    // [512]
    float* __restrict__ Y) {           // [8192][512] fp32
  __shared__ __align__(16) uint16_t As[2][4][64][8];
  __shared__ __align__(16) uint16_t Bs[2][4][128][8];

  const int tid = threadIdx.x;
  const int lane = tid & 63;
  const int wid = tid >> 6;
  const int wm = wid >> 1;
  const int wn = wid & 1;
  const int tm = blockIdx.y * 64;
  const int tn = blockIdx.x * 128;

  f32x4 acc[2][4];
  const f32x4 zero = {0.f, 0.f, 0.f, 0.f};
#pragma unroll
  for (int i = 0; i < 2; ++i)
#pragma unroll
    for (int j = 0; j < 4; ++j) acc[i][j] = zero;

  auto stage = [&](int kk, int buf) {
    // A: wave w covers kchunk w, rows = lane
    gll16(Zb + (size_t)(tm + lane) * 512 + kk * 32 + wid * 8,
          &As[buf][wid][0][0]);
#pragma unroll
    for (int s = 0; s < 2; ++s) {
      int t = wid + 4 * s;
      int kc = t >> 1;
      int cb = (t & 1) * 64;
      gll16(WT + (size_t)(tn + cb + lane) * 512 + kk * 32 + kc * 8,
            &Bs[buf][kc][cb][0]);
    }
  };

  stage(0, 0);
  __syncthreads();

  const int lr = lane & 15;
  const int lk = lane >> 4;

#pragma unroll 2
  for (int kk = 0; kk < 16; ++kk) {
    const int cur = kk & 1;
    if (kk + 1 < 16) stage(kk + 1, cur ^ 1);
    bf16x8 a[2], b[4];
#pragma unroll
    for (int mi = 0; mi < 2; ++mi)
      a[mi] = *(const bf16x8*)&As[cur][lk][wm * 32 + mi * 16 + lr][0];
#pragma unroll
    for (int nj = 0; nj < 4; ++nj)
      b[nj] = *(const bf16x8*)&Bs[cur][lk][wn * 64 + nj * 16 + lr][0];
#pragma unroll
    for (int mi = 0; mi < 2; ++mi)
#pragma unroll
      for (int nj = 0; nj < 4; ++nj)
        acc[mi][nj] = __builtin_amdgcn_mfma_f32_16x16x32_bf16(
            a[mi], b[nj], acc[mi][nj], 0, 0, 0);
    __syncthreads();
  }

#pragma unroll
  for (int mi = 0; mi < 2; ++mi)
#pragma unroll
    for (int nj = 0; nj < 4; ++nj) {
      int j = tn + wn * 64 + nj * 16 + lr;
      float bj = bias[j];
#pragma unroll
      for (int r = 0; r < 4; ++r) {
        int m = tm + wm * 32 + mi * 16 + lk * 4 + r;
        Y[(size_t)m * 512 + j] = acc[mi][nj][r] + bj;
      }
    }
}

// ---------------------------------------------------------------------------
extern "C" void kernel_launch(void* const* d_in, const int* in_sizes, int n_in,
                              void* d_out, int out_size, void* d_ws, size_t ws_size,
                              hipStream_t stream) {
  const float* x    = (const float*)d_in[0];
  // d_in[1] = grad : provably unused by the reference's dataflow.
  const float* Wqkv = (const float*)d_in[2];   // [512][1536]
  const float* Wout = (const float*)d_in[3];   // [512][512]
  const float* bout = (const float*)d_in[4];   // [512]
  float* Y = (float*)d_out;

  uint16_t* WvT = (uint16_t*)d_ws;             // 512*512 bf16 (0.5 MB)
  uint16_t* WoT = WvT + 512 * 512;             // 0.5 MB
  uint16_t* Z   = WoT + 512 * 512;             // 8192*512 bf16 (8 MB)

  dim3 tb(256);
  k_transpose_bf16<<<dim3(8, 8), tb, 0, stream>>>(Wqkv, 1536, 1024, WvT);
  k_transpose_bf16<<<dim3(8, 8), tb, 0, stream>>>(Wout, 512, 0, WoT);
  k_gemm_gelu_perm<<<dim3(4, 128), tb, 0, stream>>>(x, WvT, Z);
  k_gemm_bias<<<dim3(4, 128), tb, 0, stream>>>(Z, WoT, bout, Y);
}

// Round 2
// 46.099 us; speedup vs baseline: 1.0787x; 1.0787x over previous
//
#include <hip/hip_runtime.h>
#include <stdint.h>

// ---------------------------------------------------------------------------
// Algebraic simplification of the reference:
//   * grad / softmax / top_k results are never used (dead code).
//   * kv_sel is a broadcast -> attention softmax is uniform -> attn@v_sel = v.
//   * Net computation:
//       V = x @ W_qkv[:, 1024:1536]                      (8192x512 @ 512x512)
//       Z[bi, (pi&1)*8+hi, ni, (pi>>1)*64+d] = gelu(V[bi,pi,ni,hi*64+d])
//       Y = Z @ W_out + b_out                            (8192x512 @ 512x512)
//   with b=2, p=16, n=256, h=8, dh=64, M = b*p*n = 8192, K = N = 512.
// ---------------------------------------------------------------------------

typedef __bf16 bf16x8 __attribute__((ext_vector_type(8)));
typedef float f32x4 __attribute__((ext_vector_type(4)));
typedef unsigned short u16x4 __attribute__((ext_vector_type(4)));

#define HD __device__ __forceinline__

HD uint16_t f2bf(float f) {
  union { float f; uint32_t u; } v; v.f = f;
  uint32_t u = v.u;
  u += 0x7fffu + ((u >> 16) & 1u);   // RNE
  return (uint16_t)(u >> 16);
}

HD void gll16(const void* g, void* l) {
  __builtin_amdgcn_global_load_lds(
      (__attribute__((address_space(1))) void*)g,
      (__attribute__((address_space(3))) void*)l, 16, 0, 0);
}

// Convert 8 consecutive LDS floats -> bf16x8 MFMA fragment (RNE via HW cvt).
HD bf16x8 cvt_frag(const float* p) {
  f32x4 f0 = *(const f32x4*)p;
  f32x4 f1 = *(const f32x4*)(p + 4);
  bf16x8 r;
  r[0] = (__bf16)f0[0]; r[1] = (__bf16)f0[1];
  r[2] = (__bf16)f0[2]; r[3] = (__bf16)f0[3];
  r[4] = (__bf16)f1[0]; r[5] = (__bf16)f1[1];
  r[6] = (__bf16)f1[2]; r[7] = (__bf16)f1[3];
  return r;
}

// ---------------------------------------------------------------------------
// Both weight transposes (fp32 -> bf16, out[c][k] = in[k][coloff+c]) in one
// launch: blockIdx.z selects {W_qkv v-slice, W_out}. 64x64 tiles, 256 thr.
// ---------------------------------------------------------------------------
__global__ __launch_bounds__(256) void k_prep(
    const float* __restrict__ Wqkv, const float* __restrict__ Wout,
    uint16_t* __restrict__ WvT, uint16_t* __restrict__ WoT) {
  const float* in;
  uint16_t* out;
  int ldin, coloff;
  if (blockIdx.z == 0) { in = Wqkv; ldin = 1536; coloff = 1024; out = WvT; }
  else                 { in = Wout; ldin = 512;  coloff = 0;    out = WoT; }

  __shared__ uint16_t t[64][66];
  const int tid = threadIdx.x;
  const int tx = tid & 63;
  const int ty = tid >> 6;
  const int j0 = blockIdx.x * 64;
  const int k0 = blockIdx.y * 64;
#pragma unroll
  for (int r = 0; r < 16; ++r) {
    int k = ty * 16 + r;
    t[k][tx] = f2bf(in[(size_t)(k0 + k) * ldin + coloff + j0 + tx]);
  }
  __syncthreads();
#pragma unroll
  for (int r = 0; r < 16; ++r) {
    int j = ty * 16 + r;
    out[(size_t)(j0 + j) * 512 + k0 + tx] = t[tx][j];
  }
}

// ---------------------------------------------------------------------------
// GEMM1: V = X @ Wv, epilogue = gelu + permuted bf16 scatter into Z.
// BM=64 BN=128 BK=32, 256 thr (4 waves, each 32x64 = 2x4 frags of 16x16).
// A staged as fp32 DIRECTLY via global_load_lds (layout [kc16][64][16] f32,
// linear so gll's wave-uniform-base+lane*16 rule holds); converted to bf16 at
// fragment-read. B from pre-transposed bf16 W, layout [kc8][128][8].
// All loads per iteration are async with a single vmcnt drain at the barrier.
// ---------------------------------------------------------------------------
__global__ __launch_bounds__(256) void k_gemm1(
    const float* __restrict__ X,       // [8192][512] fp32
    const uint16_t* __restrict__ WT,   // [512][512] bf16, WT[col][k]
    uint16_t* __restrict__ Z) {        // [8192][512] bf16, permuted
  __shared__ __align__(16) float As[2][2][64][16];       // 16 KB
  __shared__ __align__(16) uint16_t Bs[2][4][128][8];    // 16 KB

  const int tid = threadIdx.x;
  const int lane = tid & 63;
  const int wid = tid >> 6;
  const int wm = wid >> 1;
  const int wn = wid & 1;
  const int tm = blockIdx.y * 64;
  const int tn = blockIdx.x * 128;

  f32x4 acc[2][4];
  const f32x4 zero = {0.f, 0.f, 0.f, 0.f};
#pragma unroll
  for (int i = 0; i < 2; ++i)
#pragma unroll
    for (int j = 0; j < 4; ++j) acc[i][j] = zero;

  auto stage = [&](int kk, int buf) {
    // A (fp32, 8 KB): wave `wid` owns rows [wid*16, wid*16+16), sweeps s = k-half.
    // LDS byte = s*4096 + row*64 + (lane&3)*16  (base wave-uniform, +lane*16).
#pragma unroll
    for (int s = 0; s < 2; ++s) {
      gll16(X + (size_t)(tm + wid * 16 + (lane >> 2)) * 512 + kk * 32 + s * 16 + (lane & 3) * 4,
            &As[buf][s][wid * 16][0]);
    }
    // B (bf16, 8 KB): as in GEMM2.
#pragma unroll
    for (int s = 0; s < 2; ++s) {
      int t = wid + 4 * s;
      int kc = t >> 1;
      int cb = (t & 1) * 64;
      gll16(WT + (size_t)(tn + cb + lane) * 512 + kk * 32 + kc * 8,
            &Bs[buf][kc][cb][0]);
    }
  };

  stage(0, 0);
  __syncthreads();

  const int lr = lane & 15;
  const int lk = lane >> 4;

#pragma unroll 2
  for (int kk = 0; kk < 16; ++kk) {
    const int cur = kk & 1;
    if (kk + 1 < 16) stage(kk + 1, cur ^ 1);
    bf16x8 a[2], b[4];
#pragma unroll
    for (int mi = 0; mi < 2; ++mi)
      a[mi] = cvt_frag(&As[cur][lk >> 1][wm * 32 + mi * 16 + lr][(lk & 1) * 8]);
#pragma unroll
    for (int nj = 0; nj < 4; ++nj)
      b[nj] = *(const bf16x8*)&Bs[cur][lk][wn * 64 + nj * 16 + lr][0];
#pragma unroll
    for (int mi = 0; mi < 2; ++mi)
#pragma unroll
      for (int nj = 0; nj < 4; ++nj)
        acc[mi][nj] = __builtin_amdgcn_mfma_f32_16x16x32_bf16(
            a[mi], b[nj], acc[mi][nj], 0, 0, 0);
    __syncthreads();
  }

  // Epilogue: exact gelu + bijective permutation, bf16 scatter.
  // V element (m=(bi,pi,ni), j=(hi,di)) -> Z row (bi,(pi&1)*8+hi,ni),
  // col (pi>>1)*64 + di.
#pragma unroll
  for (int mi = 0; mi < 2; ++mi)
#pragma unroll
    for (int nj = 0; nj < 4; ++nj)
#pragma unroll
      for (int r = 0; r < 4; ++r) {
        int m = tm + wm * 32 + mi * 16 + lk * 4 + r;
        int j = tn + wn * 64 + nj * 16 + lr;
        float v = acc[mi][nj][r];
        v = 0.5f * v * (1.0f + erff(v * 0.70710678118654752440f));
        int pi = (m >> 8) & 15;
        int mp = (m & ~(15 << 8)) | ((((pi & 1) << 3) | (j >> 6)) << 8);
        int jp = ((pi >> 1) << 6) | (j & 63);
        Z[(size_t)mp * 512 + jp] = f2bf(v);
      }
}

// ---------------------------------------------------------------------------
// GEMM2: Y = Z @ Wout + bias, fp32 out. (Unchanged — ~5 us in R0.)
// ---------------------------------------------------------------------------
__global__ __launch_bounds__(256) void k_gemm_bias(
    const uint16_t* __restrict__ Zb,   // [8192][512] bf16
    const uint16_t* __restrict__ WT,   // [512][512] bf16, WoT[col][k]
    const float* __restrict__ bias,    // [512]
    float* __restrict__ Y) {           // [8192][512] fp32
  __shared__ __align__(16) uint16_t As[2][4][64][8];
  __shared__ __align__(16) uint16_t Bs[2][4][128][8];

  const int tid = threadIdx.x;
  const int lane = tid & 63;
  const int wid = tid >> 6;
  const int wm = wid >> 1;
  const int wn = wid & 1;
  const int tm = blockIdx.y * 64;
  const int tn = blockIdx.x * 128;

  f32x4 acc[2][4];
  const f32x4 zero = {0.f, 0.f, 0.f, 0.f};
#pragma unroll
  for (int i = 0; i < 2; ++i)
#pragma unroll
    for (int j = 0; j < 4; ++j) acc[i][j] = zero;

  auto stage = [&](int kk, int buf) {
    gll16(Zb + (size_t)(tm + lane) * 512 + kk * 32 + wid * 8,
          &As[buf][wid][0][0]);
#pragma unroll
    for (int s = 0; s < 2; ++s) {
      int t = wid + 4 * s;
      int kc = t >> 1;
      int cb = (t & 1) * 64;
      gll16(WT + (size_t)(tn + cb + lane) * 512 + kk * 32 + kc * 8,
            &Bs[buf][kc][cb][0]);
    }
  };

  stage(0, 0);
  __syncthreads();

  const int lr = lane & 15;
  const int lk = lane >> 4;

#pragma unroll 2
  for (int kk = 0; kk < 16; ++kk) {
    const int cur = kk & 1;
    if (kk + 1 < 16) stage(kk + 1, cur ^ 1);
    bf16x8 a[2], b[4];
#pragma unroll
    for (int mi = 0; mi < 2; ++mi)
      a[mi] = *(const bf16x8*)&As[cur][lk][wm * 32 + mi * 16 + lr][0];
#pragma unroll
    for (int nj = 0; nj < 4; ++nj)
      b[nj] = *(const bf16x8*)&Bs[cur][lk][wn * 64 + nj * 16 + lr][0];
#pragma unroll
    for (int mi = 0; mi < 2; ++mi)
#pragma unroll
      for (int nj = 0; nj < 4; ++nj)
        acc[mi][nj] = __builtin_amdgcn_mfma_f32_16x16x32_bf16(
            a[mi], b[nj], acc[mi][nj], 0, 0, 0);
    __syncthreads();
  }

#pragma unroll
  for (int mi = 0; mi < 2; ++mi)
#pragma unroll
    for (int nj = 0; nj < 4; ++nj) {
      int j = tn + wn * 64 + nj * 16 + lr;
      float bj = bias[j];
#pragma unroll
      for (int r = 0; r < 4; ++r) {
        int m = tm + wm * 32 + mi * 16 + lk * 4 + r;
        Y[(size_t)m * 512 + j] = acc[mi][nj][r] + bj;
      }
    }
}

// ---------------------------------------------------------------------------
extern "C" void kernel_launch(void* const* d_in, const int* in_sizes, int n_in,
                              void* d_out, int out_size, void* d_ws, size_t ws_size,
                              hipStream_t stream) {
  const float* x    = (const float*)d_in[0];
  // d_in[1] = grad : provably unused by the reference's dataflow.
  const float* Wqkv = (const float*)d_in[2];   // [512][1536]
  const float* Wout = (const float*)d_in[3];   // [512][512]
  const float* bout = (const float*)d_in[4];   // [512]
  float* Y = (float*)d_out;

  uint16_t* WvT = (uint16_t*)d_ws;             // 512*512 bf16 (0.5 MB)
  uint16_t* WoT = WvT + 512 * 512;             // 0.5 MB
  uint16_t* Z   = WoT + 512 * 512;             // 8192*512 bf16 (8 MB)

  dim3 tb(256);
  k_prep<<<dim3(8, 8, 2), tb, 0, stream>>>(Wqkv, Wout, WvT, WoT);
  k_gemm1<<<dim3(4, 128), tb, 0, stream>>>(x, WvT, Z);
  k_gemm_bias<<<dim3(4, 128), tb, 0, stream>>>(Z, WoT, bout, Y);
}